// Round 5
// baseline (1155.471 us; speedup 1.0000x reference)
//
#include <hip/hip_runtime.h>
#include <hip/hip_bf16.h>
#include <math.h>

// ---------------------------------------------------------------------------
// PromptGenerate: DWT->E->smooth->conv1+BN+GELU->conv2->sigmoid (sal, 512x512)
//  -> bilinear 2x upsample (masks), boxes from mask>0.5, greedy-NMS peak coords
// Outputs (flat f32): coords (8,10,2)=160 | labels (8,10)=80 | boxes (8,4)=32 |
//                     masks (8,1,1024,1024)=8388608
// R1: k_resize atomic-free (1.2 ms box-atomic ping-pong removed).
// R2: k_conv register-blocked 4 px/thread + folded BN; const gaussian weights.
// R3: __launch_bounds__(256,2) == 128-VGPR cap on gfx950 -> spill; removed.
// R4: k_conv weights via UNIFORM scalar loads (s_load -> v_fma s-operand);
//     LDS removed from k_conv entirely -- R3 version was LDS-pipe-bound
//     (864 ds_read_b128/thread, 8 waves sharing 1 LDS pipe, VALUBusy 33%).
//     k_prep packs [ci*9+k][co] weights + BN scale/shift into ws.
//     hist1 caches peak-flag mask; hist2/compact reuse it (no 9-pt recheck).
// ---------------------------------------------------------------------------

#define CHW 262144          // 512*512
#define FULLHW 1048576      // 1024*1024

static constexpr size_t OFF_SAL   = 0;                       // 8*CHW*4 = 8388608
static constexpr size_t OFF_HIST1 = 8388608;                 // 2*8*2048*4 = 131072
static constexpr size_t OFF_HIST2 = OFF_HIST1 + 131072;
static constexpr size_t OFF_THR   = OFF_HIST2 + 131072;      // 2*8*4 ints = 256
static constexpr size_t OFF_CNT   = OFF_THR + 256;           // 16 u32 (pad 256)
static constexpr size_t OFF_BOX   = OFF_CNT + 256;           // 8*4 ints (pad 256)
static constexpr size_t OFF_CAND  = OFF_BOX + 256;           // 2*8*1024*8 = 131072
static constexpr size_t OFF_PART  = OFF_CAND + 131072;       // 8*256*4 ints = 32768
static constexpr size_t OFF_WPACK = OFF_PART + 32768;        // 3585 f32 pad 16384
static constexpr size_t OFF_PKM   = OFF_WPACK + 16384;       // 8*CHW u8 = 2097152
static constexpr size_t OFF_FREQ  = OFF_PKM + 2097152;       // nb*12*CHW*4

// wpack layout (floats): [0,3456) weights [ci*9+k][co] | [3456,3488) bias1 |
// [3488,3520) bn scale | [3520,3552) bn shift | [3552,3584) w2 | [3584] b2
#define WP_B1  3456
#define WP_SC  3488
#define WP_SH  3520
#define WP_W2  3552
#define WP_B2  3584

// ---------------------------------------------------------------- init
__global__ void k_init(unsigned* __restrict__ h, unsigned* __restrict__ cnt) {
  int i = blockIdx.x * 256 + threadIdx.x;
  if (i < 65536) h[i] = 0;                       // hist1+hist2 (contiguous)
  if (i < 16) cnt[i] = 0;
}

// ---------------------------------------------------------------- weight pack
__global__ void k_prep(const float* __restrict__ w1, const float* __restrict__ b1,
                       const float* __restrict__ gam, const float* __restrict__ bet,
                       const float* __restrict__ mean, const float* __restrict__ var,
                       const float* __restrict__ w2, const float* __restrict__ b2,
                       float* __restrict__ wp) {
  int i = blockIdx.x * 256 + threadIdx.x;
  if (i < 3456) {
    int co = i & 31, rest = i >> 5;              // rest = ci*9+k
    wp[i] = w1[co * 108 + rest];
  } else if (i < WP_SC) {
    wp[i] = b1[i - WP_B1];
  } else if (i < WP_SH) {
    int c = i - WP_SC;
    wp[i] = gam[c] / sqrtf(var[c] + 1e-5f);
  } else if (i < WP_W2) {
    int c = i - WP_SH;
    wp[i] = bet[c] - mean[c] * gam[c] / sqrtf(var[c] + 1e-5f);
  } else if (i < WP_B2) {
    wp[i] = w2[i - WP_W2];
  } else if (i == WP_B2) {
    wp[i] = b2[0];
  }
}

// ---------------------------------------------------------------- freq ch 0..9
__global__ __launch_bounds__(256) void k_freq(const float* __restrict__ rgb,
                                              const float* __restrict__ dep,
                                              float* __restrict__ freq, int b0) {
  int t = blockIdx.x * 256 + threadIdx.x;        // [0, 131072)
  int bi = blockIdx.y;
  int b = b0 + bi;
  int xp = t & 255, y = t >> 8;                  // xp: pair idx, outputs x=2xp,2xp+1
  const float* base = rgb + (size_t)b * 3 * FULLHW + (size_t)(2 * y) * 1024 + 4 * xp;
  float4 R0 = *(const float4*)(base);
  float4 R1 = *(const float4*)(base + 1024);
  float4 G0 = *(const float4*)(base + FULLHW);
  float4 G1 = *(const float4*)(base + FULLHW + 1024);
  float4 Bl0 = *(const float4*)(base + 2 * FULLHW);
  float4 Bl1 = *(const float4*)(base + 2 * FULLHW + 1024);
  const float* dbase = dep + (size_t)b * FULLHW + (size_t)(2 * y) * 1024 + 4 * xp;
  float4 D0 = *(const float4*)(dbase);
  float4 D1 = *(const float4*)(dbase + 1024);

  float gt[4], gb[4], dt[4], db_[4];
  gt[0] = (R0.x + G0.x + Bl0.x) / 3.0f; gt[1] = (R0.y + G0.y + Bl0.y) / 3.0f;
  gt[2] = (R0.z + G0.z + Bl0.z) / 3.0f; gt[3] = (R0.w + G0.w + Bl0.w) / 3.0f;
  gb[0] = (R1.x + G1.x + Bl1.x) / 3.0f; gb[1] = (R1.y + G1.y + Bl1.y) / 3.0f;
  gb[2] = (R1.z + G1.z + Bl1.z) / 3.0f; gb[3] = (R1.w + G1.w + Bl1.w) / 3.0f;
  dt[0] = D0.x; dt[1] = D0.y; dt[2] = D0.z; dt[3] = D0.w;
  db_[0] = D1.x; db_[1] = D1.y; db_[2] = D1.z; db_[3] = D1.w;

  float oLL[2], oLH[2], oHL[2], oHH[2], oEr[2];
  float eLL[2], eLH[2], eHL[2], eHH[2], oEd[2];
  #pragma unroll
  for (int j = 0; j < 2; ++j) {
    float a = gt[2 * j] * 0.5f, bb = gb[2 * j] * 0.5f;
    float c = gt[2 * j + 1] * 0.5f, d = gb[2 * j + 1] * 0.5f;
    oLL[j] = a + bb; oLH[j] = a - bb; oHL[j] = c + d; oHH[j] = c - d;
    oEr[j] = sqrtf(oLH[j] * oLH[j] + oHL[j] * oHL[j] + oHH[j] * oHH[j] + 1e-8f);
    float da = dt[2 * j] * 0.5f, db2 = db_[2 * j] * 0.5f;
    float dc = dt[2 * j + 1] * 0.5f, dd = db_[2 * j + 1] * 0.5f;
    eLL[j] = da + db2; eLH[j] = da - db2; eHL[j] = dc + dd; eHH[j] = dc - dd;
    oEd[j] = sqrtf(eLH[j] * eLH[j] + eHL[j] * eHL[j] + eHH[j] * eHH[j] + 1e-8f);
  }
  float* f = freq + (size_t)bi * 12 * CHW + y * 512 + 2 * xp;
  *(float2*)(f + 0 * CHW) = make_float2(oLL[0], oLL[1]);
  *(float2*)(f + 1 * CHW) = make_float2(oLH[0], oLH[1]);
  *(float2*)(f + 2 * CHW) = make_float2(oHL[0], oHL[1]);
  *(float2*)(f + 3 * CHW) = make_float2(oHH[0], oHH[1]);
  *(float2*)(f + 4 * CHW) = make_float2(eLL[0], eLL[1]);
  *(float2*)(f + 5 * CHW) = make_float2(eLH[0], eLH[1]);
  *(float2*)(f + 6 * CHW) = make_float2(eHL[0], eHL[1]);
  *(float2*)(f + 7 * CHW) = make_float2(eHH[0], eHH[1]);
  *(float2*)(f + 8 * CHW) = make_float2(oEr[0], oEr[1]);
  *(float2*)(f + 9 * CHW) = make_float2(oEd[0], oEd[1]);
}

// ---------------------------------------------------------------- freq ch 10,11
__constant__ float GW[25] = {
  0.00296901f, 0.01330621f, 0.02193824f, 0.01330621f, 0.00296901f,
  0.01330621f, 0.05963435f, 0.09832035f, 0.05963435f, 0.01330621f,
  0.02193824f, 0.09832035f, 0.16210276f, 0.09832035f, 0.02193824f,
  0.01330621f, 0.05963435f, 0.09832035f, 0.05963435f, 0.01330621f,
  0.00296901f, 0.01330621f, 0.02193824f, 0.01330621f, 0.00296901f};

__global__ __launch_bounds__(256) void k_smooth(float* __restrict__ freq) {
  int t = blockIdx.x * 256 + threadIdx.x;
  int bi = blockIdx.y;
  int x = t & 511, y = t >> 9;
  float* fb_ = freq + (size_t)bi * 12 * CHW;
  #pragma unroll
  for (int ch = 0; ch < 2; ++ch) {
    const float* fin = fb_ + (8 + ch) * CHW;
    float acc = 0.0f;
    #pragma unroll
    for (int i = 0; i < 5; ++i) {
      int yy = y + i - 2;
      if (yy < 0 || yy > 511) continue;
      #pragma unroll
      for (int j = 0; j < 5; ++j) {
        int xx = x + j - 2;
        if (xx < 0 || xx > 511) continue;
        acc += GW[i * 5 + j] * fin[yy * 512 + xx];
      }
    }
    fb_[(10 + ch) * CHW + t] = acc;
  }
}

// ---------------------------------------------------------------- conv fused
// 4 px/thread (64x16 tile per block). Weights read as WAVE-UNIFORM scalars
// from packed global buffer -> s_load + v_fma with SGPR operand; zero LDS.
__device__ __forceinline__ void load_win(const float* __restrict__ fp, int y,
                                         int x0, float* __restrict__ v) {
  #pragma unroll
  for (int r = 0; r < 3; ++r) {
    int yy = y + r - 1;
    bool rv = (yy >= 0 && yy < 512);
    const float* rp = fp + yy * 512;
    float4 m = rv ? *(const float4*)(rp + x0) : make_float4(0.f, 0.f, 0.f, 0.f);
    v[r * 6 + 1] = m.x; v[r * 6 + 2] = m.y; v[r * 6 + 3] = m.z; v[r * 6 + 4] = m.w;
    v[r * 6 + 0] = (rv && x0 > 0) ? rp[x0 - 1] : 0.0f;
    v[r * 6 + 5] = (rv && x0 + 4 < 512) ? rp[x0 + 4] : 0.0f;
  }
}

__global__ __launch_bounds__(256) void k_conv(const float* __restrict__ freq,
    const float* __restrict__ wp, float* __restrict__ sal, int b0) {
  int tx = threadIdx.x, ty = threadIdx.y;
  int x0 = blockIdx.x * 64 + tx * 4;
  int y = blockIdx.y * 16 + ty;
  int bi = blockIdx.z;
  const float* fb_ = freq + (size_t)bi * 12 * CHW;

  float acc[4][32];
  #pragma unroll
  for (int co = 0; co < 32; ++co) {
    float bv = wp[WP_B1 + co];                   // uniform -> SGPR
    acc[0][co] = bv; acc[1][co] = bv; acc[2][co] = bv; acc[3][co] = bv;
  }

  float v[18], nv[18];
  load_win(fb_, y, x0, v);

  auto fma_ci = [&](int ci, const float* w) {
    const float* wb = wp + ci * 288;             // uniform base
    #pragma unroll
    for (int ky = 0; ky < 3; ++ky) {
      #pragma unroll
      for (int kx = 0; kx < 3; ++kx) {
        const float* wk = wb + (ky * 3 + kx) * 32;
        float a0 = w[ky * 6 + kx],     a1 = w[ky * 6 + kx + 1];
        float a2 = w[ky * 6 + kx + 2], a3 = w[ky * 6 + kx + 3];
        #pragma unroll
        for (int co = 0; co < 32; ++co) {
          float wv = wk[co];                     // uniform -> s_load, SGPR fma
          acc[0][co] += wv * a0;
          acc[1][co] += wv * a1;
          acc[2][co] += wv * a2;
          acc[3][co] += wv * a3;
        }
      }
    }
  };

  #pragma unroll 1
  for (int ci = 0; ci < 12; ci += 2) {           // ping-pong windows, no copies
    load_win(fb_ + (ci + 1) * CHW, y, x0, nv);
    fma_ci(ci, v);
    if (ci + 2 < 12) load_win(fb_ + (ci + 2) * CHW, y, x0, v);
    fma_ci(ci + 1, nv);
  }

  float b2v = wp[WP_B2];
  float res[4];
  #pragma unroll
  for (int px = 0; px < 4; ++px) {
    float s2 = b2v;
    #pragma unroll
    for (int co = 0; co < 32; ++co) {
      float t = acc[px][co] * wp[WP_SC + co] + wp[WP_SH + co];
      float t3 = t * t * t;
      float gl = 0.5f * t * (1.0f + tanhf(0.7978845608028654f * (t + 0.044715f * t3)));
      s2 += gl * wp[WP_W2 + co];
    }
    res[px] = 1.0f / (1.0f + expf(-s2));
  }
  *(float4*)(sal + (size_t)(b0 + bi) * CHW + y * 512 + x0) =
      make_float4(res[0], res[1], res[2], res[3]);
}

// ---------------------------------------------------------------- resize + box partials
__global__ __launch_bounds__(256) void k_resize(const float* __restrict__ sal,
                                                float* __restrict__ masks,
                                                int* __restrict__ part) {
  int b = blockIdx.y;
  int blk = blockIdx.x;
  int t = threadIdx.x;
  const float* sp = sal + (size_t)b * CHW;
  float* mp = masks + (size_t)b * FULLHW;
  int mnX = 0x7FFFFFFF, mxX = -1, mnY = 0x7FFFFFFF, mxY = -1;
  int c0 = 4 * t;
  #pragma unroll
  for (int r = 0; r < 4; ++r) {
    int Y = blk * 4 + r;
    int y0 = (Y - 1) >> 1;
    float wy = (Y & 1) ? 0.25f : 0.75f;
    int y0c = y0 < 0 ? 0 : y0, y1c = (y0 + 1 > 511) ? 511 : y0 + 1;
    const float* r0 = sp + y0c * 512;
    const float* r1 = sp + y1c * 512;
    float o[4];
    #pragma unroll
    for (int j = 0; j < 4; ++j) {
      int X = c0 + j;
      int x0 = (X - 1) >> 1;
      float wx = (X & 1) ? 0.25f : 0.75f;
      int x0c = x0 < 0 ? 0 : x0, x1c = (x0 + 1 > 511) ? 511 : x0 + 1;
      float v00 = r0[x0c], v01 = r0[x1c], v10 = r1[x0c], v11 = r1[x1c];
      o[j] = (1.0f - wy) * ((1.0f - wx) * v00 + wx * v01)
           + wy * ((1.0f - wx) * v10 + wx * v11);
      if (o[j] > 0.5f) {
        mnX = min(mnX, X); mxX = max(mxX, X);
        mnY = min(mnY, Y); mxY = max(mxY, Y);
      }
    }
    *(float4*)(mp + (size_t)Y * 1024 + c0) = make_float4(o[0], o[1], o[2], o[3]);
  }
  __shared__ int s0[256], s1[256], s2[256], s3[256];
  s0[t] = mnX; s1[t] = mxX; s2[t] = mnY; s3[t] = mxY;
  __syncthreads();
  for (int off = 128; off > 0; off >>= 1) {
    if (t < off) {
      s0[t] = min(s0[t], s0[t + off]); s1[t] = max(s1[t], s1[t + off]);
      s2[t] = min(s2[t], s2[t + off]); s3[t] = max(s3[t], s3[t + off]);
    }
    __syncthreads();
  }
  if (t == 0) {
    int* pp = part + (b * 256 + blk) * 4;
    pp[0] = s0[0]; pp[1] = s1[0]; pp[2] = s2[0]; pp[3] = s3[0];
  }
}

// ---------------------------------------------------------------- box reduce
__global__ __launch_bounds__(256) void k_boxreduce(const int* __restrict__ part,
                                                   int* __restrict__ box) {
  int b = blockIdx.x, t = threadIdx.x;
  const int* pp = part + (b * 256 + t) * 4;
  __shared__ int s0[256], s1[256], s2[256], s3[256];
  s0[t] = pp[0]; s1[t] = pp[1]; s2[t] = pp[2]; s3[t] = pp[3];
  __syncthreads();
  for (int off = 128; off > 0; off >>= 1) {
    if (t < off) {
      s0[t] = min(s0[t], s0[t + off]); s1[t] = max(s1[t], s1[t + off]);
      s2[t] = min(s2[t], s2[t + off]); s3[t] = max(s3[t], s3[t + off]);
    }
    __syncthreads();
  }
  if (t == 0) {
    box[b * 4 + 0] = s0[0];   // cmin
    box[b * 4 + 1] = s2[0];   // rmin
    box[b * 4 + 2] = s1[0];   // cmax
    box[b * 4 + 3] = s3[0];   // rmax
  }
}

// ---------------------------------------------------------------- peak helper
__device__ inline bool is_peak(const float* __restrict__ sp, int x, int y, float& sv) {
  float s = sp[y * 512 + x];
  sv = s;
  if (!(s > 0.0f)) return false;
  int x0 = (x > 0) ? x - 1 : x, x1 = (x < 511) ? x + 1 : x;
  int y0 = (y > 0) ? y - 1 : y, y1 = (y < 511) ? y + 1 : y;
  for (int yy = y0; yy <= y1; ++yy)
    for (int xx = x0; xx <= x1; ++xx)
      if (sp[yy * 512 + xx] > s) return false;     // s >= all neighbors == (s==maxpool)
  return true;
}

// ---------------------------------------------------------------- level-1 hist (+peak mask)
__global__ __launch_bounds__(256) void k_hist1(const float* __restrict__ sal,
                                               unsigned* __restrict__ hist,
                                               unsigned char* __restrict__ pkm) {
  __shared__ unsigned sH[4096];                   // [class][2048]
  int b = blockIdx.y, tid = threadIdx.x;
  for (int i = tid; i < 4096; i += 256) sH[i] = 0;
  __syncthreads();
  const float* sp = sal + (size_t)b * CHW;
  int base = blockIdx.x * 8192;
  for (int it = 0; it < 32; ++it) {
    int p = base + it * 256 + tid;
    int x = p & 511, y = p >> 9;
    float s;
    bool pk = is_peak(sp, x, y, s);
    pkm[(size_t)b * CHW + p] = pk ? 1 : 0;
    unsigned bin = (__float_as_uint(s) >> 21) & 2047;
    atomicAdd(&sH[(pk ? 0 : 2048) + bin], 1u);
  }
  __syncthreads();
  for (int i = tid; i < 4096; i += 256) {
    unsigned v = sH[i];
    if (v) atomicAdd(&hist[(i >= 2048 ? 16384 : 0) + b * 2048 + (i & 2047)], v);
  }
}

// ---------------------------------------------------------------- radix scan
__global__ __launch_bounds__(256) void k_scan(const unsigned* __restrict__ hist,
                                              int* __restrict__ thr, int level) {
  int c = blockIdx.x, b = blockIdx.y, t = threadIdx.x;
  __shared__ unsigned sBins[2048];
  __shared__ unsigned sS[256];
  __shared__ int sT;
  const unsigned* hp = hist + c * 16384 + b * 2048;
  unsigned part = 0;
  for (int r = 0; r < 8; ++r) {
    unsigned v = hp[t * 8 + r];
    sBins[t * 8 + r] = v;
    part += v;
  }
  sS[t] = part;
  __syncthreads();
  for (int off = 1; off < 256; off <<= 1) {
    unsigned add = (t + off < 256) ? sS[t + off] : 0;
    __syncthreads();
    sS[t] += add;
    __syncthreads();
  }
  int K = (c == 0) ? 512 : 10;
  int* tb = thr + (c * 8 + b) * 4;
  if (level == 1) { K -= tb[1]; if (K < 1) K = 1; }
  if (t == 0) sT = -1;
  __syncthreads();
  if (sS[t] >= (unsigned)K && (t == 255 || sS[t + 1] < (unsigned)K)) sT = t;
  __syncthreads();
  if (t == 0) {
    int T = 0;
    unsigned run = 0;
    if (sT >= 0) {
      int ts = sT;
      run = (ts < 255) ? sS[ts + 1] : 0;
      for (int r = 7; r >= 0; --r) {
        unsigned v = sBins[ts * 8 + r];
        run += v;
        if (run >= (unsigned)K) { T = ts * 8 + r; run -= v; break; }
      }
    } else {
      T = 0;
      run = sS[0] - sBins[0];                     // suffix(1); take everything
    }
    if (level == 0) { tb[0] = T; tb[1] = (int)run; }
    else           { tb[2] = (tb[0] << 11) | T; }
  }
}

// ---------------------------------------------------------------- level-2 hist
__global__ __launch_bounds__(256) void k_hist2(const float* __restrict__ sal,
                                               const unsigned char* __restrict__ pkm,
                                               const int* __restrict__ thr,
                                               unsigned* __restrict__ hist2) {
  int b = blockIdx.y;
  int p = blockIdx.x * 256 + threadIdx.x;
  const float* sp = sal + (size_t)b * CHW;
  bool pk = pkm[(size_t)b * CHW + p] != 0;
  float s = sp[p];
  int c = pk ? 0 : 1;
  unsigned bits = __float_as_uint(s);
  if ((int)(bits >> 21) == thr[(c * 8 + b) * 4])
    atomicAdd(&hist2[c * 16384 + b * 2048 + ((bits >> 10) & 2047)], 1u);
}

// ---------------------------------------------------------------- compact
__global__ __launch_bounds__(256) void k_compact(const float* __restrict__ sal,
                                                 const unsigned char* __restrict__ pkm,
                                                 const int* __restrict__ thr,
                                                 unsigned* __restrict__ cnt,
                                                 unsigned long long* __restrict__ cand) {
  int b = blockIdx.y;
  int p = blockIdx.x * 256 + threadIdx.x;
  const float* sp = sal + (size_t)b * CHW;
  bool pk = pkm[(size_t)b * CHW + p] != 0;
  float s = sp[p];
  int c = pk ? 0 : 1;
  unsigned bits = __float_as_uint(s);
  unsigned q = (unsigned)thr[(c * 8 + b) * 4 + 2];
  if ((bits >> 10) >= q) {
    unsigned pos = atomicAdd(&cnt[c * 8 + b], 1u);
    if (pos < 1024)
      cand[((size_t)(c * 8 + b) << 10) + pos] =
          ((unsigned long long)bits << 32) | (unsigned)(~p);   // score desc, idx asc
  }
}

// ---------------------------------------------------------------- sort + NMS
__device__ inline void bitonic1024_desc(unsigned long long* sKey) {
  int t = threadIdx.x;
  for (unsigned k = 2; k <= 1024; k <<= 1) {
    for (unsigned j = k >> 1; j > 0; j >>= 1) {
      __syncthreads();
      #pragma unroll
      for (int e = 0; e < 2; ++e) {
        unsigned i = (unsigned)t + (unsigned)e * 512u;
        unsigned l = i ^ j;
        if (l > i) {
          unsigned long long a = sKey[i], bb = sKey[l];
          if (((i & k) == 0) ? (a < bb) : (a > bb)) { sKey[i] = bb; sKey[l] = a; }
        }
      }
    }
  }
  __syncthreads();
}

__global__ __launch_bounds__(512) void k_nms(const unsigned long long* __restrict__ cand,
                                             const unsigned* __restrict__ cnt,
                                             float* __restrict__ outc) {
  __shared__ unsigned long long sKey[1024];
  __shared__ unsigned sIdx[512];
  __shared__ int sAvail[512];
  __shared__ int sSel[16];
  int b = blockIdx.x, t = threadIdx.x;
  int Cp = (int)cnt[b]; if (Cp > 1024) Cp = 1024;
  const unsigned long long* cp = cand + ((size_t)b << 10);
  sKey[t] = (t < Cp) ? cp[t] : 0ULL;
  sKey[t + 512] = (t + 512 < Cp) ? cp[t + 512] : 0ULL;
  bitonic1024_desc(sKey);
  sIdx[t] = (unsigned)(~sKey[t]);
  int ncand = (Cp < 512) ? Cp : 512;              // K_PEAKS cap
  sAvail[t] = (t < ncand) ? 1 : 0;
  __syncthreads();
  int nsel = 0;
  for (int i = 0; i < 512 && nsel < 10; ++i) {
    if (sAvail[i] != 0) {                         // uniform branch
      unsigned pi = sIdx[i];
      int xi = (int)(pi & 511), yi = (int)(pi >> 9);
      if (t > i && sAvail[t]) {
        int dx = (int)(sIdx[t] & 511) - xi;
        int dy = (int)(sIdx[t] >> 9) - yi;
        if (dx * dx + dy * dy < 625) sAvail[t] = 0;   // dist < 25
      }
      if (t == 0) sSel[nsel] = (int)pi;
      ++nsel;
      __syncthreads();
    }
  }
  __syncthreads();
  // fallback: top-10 non-peak pixels
  int Cf = (int)cnt[8 + b]; if (Cf > 1024) Cf = 1024;
  const unsigned long long* cf = cand + ((size_t)(8 + b) << 10);
  sKey[t] = (t < Cf) ? cf[t] : 0ULL;
  sKey[t + 512] = (t + 512 < Cf) ? cf[t + 512] : 0ULL;
  bitonic1024_desc(sKey);
  if (t < 10) {
    int fi;
    if (t < nsel) fi = sSel[t];
    else { int r = t - nsel; if (r > 9) r = 9; fi = (int)((unsigned)(~sKey[r])); }
    outc[((size_t)b * 10 + t) * 2 + 0] = (float)(fi & 511) * (1.0f / 512.0f);
    outc[((size_t)b * 10 + t) * 2 + 1] = (float)(fi >> 9) * (1.0f / 512.0f);
  }
}

// ---------------------------------------------------------------- finalize
__global__ void k_final(const int* __restrict__ box, float* __restrict__ out) {
  int t = threadIdx.x;
  if (t < 80) out[160 + t] = 1.0f;                // labels
  if (t < 8) {
    const int* bp = box + t * 4;
    float x0, y0, x1, y1;
    if (bp[3] < 0) { x0 = 0.0f; y0 = 0.0f; x1 = 1023.0f; y1 = 1023.0f; }
    else { x0 = (float)bp[0]; y0 = (float)bp[1]; x1 = (float)bp[2]; y1 = (float)bp[3]; }
    out[240 + t * 4 + 0] = x0;
    out[240 + t * 4 + 1] = y0;
    out[240 + t * 4 + 2] = x1;
    out[240 + t * 4 + 3] = y1;
  }
}

// ---------------------------------------------------------------------------
extern "C" void kernel_launch(void* const* d_in, const int* in_sizes, int n_in,
                              void* d_out, int out_size, void* d_ws, size_t ws_size,
                              hipStream_t stream) {
  const float* rgb  = (const float*)d_in[0];
  const float* dep  = (const float*)d_in[1];
  const float* w1   = (const float*)d_in[2];
  const float* b1   = (const float*)d_in[3];
  const float* gam  = (const float*)d_in[4];
  const float* bet  = (const float*)d_in[5];
  const float* bmn  = (const float*)d_in[6];
  const float* bvr  = (const float*)d_in[7];
  const float* w2   = (const float*)d_in[8];
  const float* b2   = (const float*)d_in[9];
  float* out = (float*)d_out;
  char* ws = (char*)d_ws;

  float* sal = (float*)(ws + OFF_SAL);
  unsigned* hist1 = (unsigned*)(ws + OFF_HIST1);
  unsigned* hist2 = (unsigned*)(ws + OFF_HIST2);
  int* thr = (int*)(ws + OFF_THR);
  unsigned* cnt = (unsigned*)(ws + OFF_CNT);
  int* box = (int*)(ws + OFF_BOX);
  unsigned long long* cand = (unsigned long long*)(ws + OFF_CAND);
  int* part = (int*)(ws + OFF_PART);
  float* wpack = (float*)(ws + OFF_WPACK);
  unsigned char* pkm = (unsigned char*)(ws + OFF_PKM);
  float* freq = (float*)(ws + OFF_FREQ);

  // chunk batches so freq buffer fits in ws
  size_t perB = (size_t)12 * CHW * 4;
  long long avail = (long long)ws_size - (long long)OFF_FREQ;
  int nb = 1;
  if (avail >= (long long)perB) {
    long long m = avail / (long long)perB;
    nb = (m > 8) ? 8 : (int)m;
  }

  k_init<<<256, 256, 0, stream>>>(hist1, cnt);
  k_prep<<<15, 256, 0, stream>>>(w1, b1, gam, bet, bmn, bvr, w2, b2, wpack);

  for (int b0 = 0; b0 < 8; b0 += nb) {
    int nbc = (8 - b0 < nb) ? (8 - b0) : nb;
    k_freq<<<dim3(512, nbc), 256, 0, stream>>>(rgb, dep, freq, b0);
    k_smooth<<<dim3(1024, nbc), 256, 0, stream>>>(freq);
    k_conv<<<dim3(8, 32, nbc), dim3(16, 16), 0, stream>>>(freq, wpack, sal, b0);
  }

  k_resize<<<dim3(256, 8), 256, 0, stream>>>(sal, out + 272, part);
  k_boxreduce<<<8, 256, 0, stream>>>(part, box);
  k_hist1<<<dim3(32, 8), 256, 0, stream>>>(sal, hist1, pkm);
  k_scan<<<dim3(2, 8), 256, 0, stream>>>(hist1, thr, 0);
  k_hist2<<<dim3(1024, 8), 256, 0, stream>>>(sal, pkm, thr, hist2);
  k_scan<<<dim3(2, 8), 256, 0, stream>>>(hist2, thr, 1);
  k_compact<<<dim3(1024, 8), 256, 0, stream>>>(sal, pkm, thr, cnt, cand);
  k_nms<<<8, 512, 0, stream>>>(cand, cnt, out);
  k_final<<<1, 128, 0, stream>>>(box, out);
}

// Round 6
// 966.236 us; speedup vs baseline: 1.1958x; 1.1958x over previous
//
#include <hip/hip_runtime.h>
#include <hip/hip_bf16.h>
#include <math.h>

// ---------------------------------------------------------------------------
// PromptGenerate: DWT->E->smooth->conv1+BN+GELU->conv2->sigmoid (sal, 512x512)
//  -> bilinear 2x upsample (masks), boxes from mask>0.5, greedy-NMS peak coords
// Outputs (flat f32): coords (8,10,2)=160 | labels (8,10)=80 | boxes (8,4)=32 |
//                     masks (8,1,1024,1024)=8388608
// R1: k_resize atomic-free (1.2 ms box-atomic ping-pong removed).
// R2: k_conv register-blocked 4 px/thread + folded BN; const gaussian weights.
// R3: __launch_bounds__(256,2) == 128-VGPR cap on gfx950 -> spill; removed.
// R4: k_conv weights via uniform s_load; zero LDS. VALUBusy 52%, occ 11.6%:
//     s_load batches (288 dwords/ci through ~60 SGPRs) expose lgkmcnt waits
//     at 2 waves/SIMD (VGPR=200).
// R5: co-SPLIT across the 4 waves of each block: wave w does co[8w,8w+8).
//     acc[4][8]=32 VGPR -> ~110 total -> 4 waves/SIMD; 72 weight dwords/ci
//     per wave (8:1 FMA:s_load). Cross-wave epilogue sum via 4KB LDS.
//     k_hist1 grid x4; k_init+k_prep merged; k_final folded into
//     k_boxreduce (boxes) + k_nms (labels).
// ---------------------------------------------------------------------------

#define CHW 262144          // 512*512
#define FULLHW 1048576      // 1024*1024

static constexpr size_t OFF_SAL   = 0;                       // 8*CHW*4 = 8388608
static constexpr size_t OFF_HIST1 = 8388608;                 // 2*8*2048*4 = 131072
static constexpr size_t OFF_HIST2 = OFF_HIST1 + 131072;
static constexpr size_t OFF_THR   = OFF_HIST2 + 131072;      // 2*8*4 ints = 256
static constexpr size_t OFF_CNT   = OFF_THR + 256;           // 16 u32 (pad 256)
static constexpr size_t OFF_BOX   = OFF_CNT + 256;           // 8*4 ints (pad 256)
static constexpr size_t OFF_CAND  = OFF_BOX + 256;           // 2*8*1024*8 = 131072
static constexpr size_t OFF_PART  = OFF_CAND + 131072;       // 8*256*4 ints = 32768
static constexpr size_t OFF_WPACK = OFF_PART + 32768;        // 3585 f32 pad 16384
static constexpr size_t OFF_PKM   = OFF_WPACK + 16384;       // 8*CHW u8 = 2097152
static constexpr size_t OFF_FREQ  = OFF_PKM + 2097152;       // nb*12*CHW*4

// wpack layout (floats): [0,3456) weights [ci*9+k][co] | [3456,3488) bias1 |
// [3488,3520) bn scale | [3520,3552) bn shift | [3552,3584) w2 | [3584] b2
#define WP_B1  3456
#define WP_SC  3488
#define WP_SH  3520
#define WP_W2  3552
#define WP_B2  3584

// ---------------------------------------------------------------- init + weight pack
__global__ void k_init(unsigned* __restrict__ h, unsigned* __restrict__ cnt,
                       const float* __restrict__ w1, const float* __restrict__ b1,
                       const float* __restrict__ gam, const float* __restrict__ bet,
                       const float* __restrict__ mean, const float* __restrict__ var,
                       const float* __restrict__ w2, const float* __restrict__ b2,
                       float* __restrict__ wp) {
  int i = blockIdx.x * 256 + threadIdx.x;
  if (i < 65536) h[i] = 0;                       // hist1+hist2 (contiguous)
  if (i < 16) cnt[i] = 0;
  if (i < 3456) {
    int co = i & 31, rest = i >> 5;              // rest = ci*9+k
    wp[i] = w1[co * 108 + rest];
  } else if (i < WP_SC) {
    wp[i] = b1[i - WP_B1];
  } else if (i < WP_SH) {
    int c = i - WP_SC;
    wp[i] = gam[c] / sqrtf(var[c] + 1e-5f);
  } else if (i < WP_W2) {
    int c = i - WP_SH;
    wp[i] = bet[c] - mean[c] * gam[c] / sqrtf(var[c] + 1e-5f);
  } else if (i < WP_B2) {
    wp[i] = w2[i - WP_W2];
  } else if (i == WP_B2) {
    wp[i] = b2[0];
  }
}

// ---------------------------------------------------------------- freq ch 0..9
__global__ __launch_bounds__(256) void k_freq(const float* __restrict__ rgb,
                                              const float* __restrict__ dep,
                                              float* __restrict__ freq, int b0) {
  int t = blockIdx.x * 256 + threadIdx.x;        // [0, 131072)
  int bi = blockIdx.y;
  int b = b0 + bi;
  int xp = t & 255, y = t >> 8;                  // xp: pair idx, outputs x=2xp,2xp+1
  const float* base = rgb + (size_t)b * 3 * FULLHW + (size_t)(2 * y) * 1024 + 4 * xp;
  float4 R0 = *(const float4*)(base);
  float4 R1 = *(const float4*)(base + 1024);
  float4 G0 = *(const float4*)(base + FULLHW);
  float4 G1 = *(const float4*)(base + FULLHW + 1024);
  float4 Bl0 = *(const float4*)(base + 2 * FULLHW);
  float4 Bl1 = *(const float4*)(base + 2 * FULLHW + 1024);
  const float* dbase = dep + (size_t)b * FULLHW + (size_t)(2 * y) * 1024 + 4 * xp;
  float4 D0 = *(const float4*)(dbase);
  float4 D1 = *(const float4*)(dbase + 1024);

  float gt[4], gb[4], dt[4], db_[4];
  gt[0] = (R0.x + G0.x + Bl0.x) / 3.0f; gt[1] = (R0.y + G0.y + Bl0.y) / 3.0f;
  gt[2] = (R0.z + G0.z + Bl0.z) / 3.0f; gt[3] = (R0.w + G0.w + Bl0.w) / 3.0f;
  gb[0] = (R1.x + G1.x + Bl1.x) / 3.0f; gb[1] = (R1.y + G1.y + Bl1.y) / 3.0f;
  gb[2] = (R1.z + G1.z + Bl1.z) / 3.0f; gb[3] = (R1.w + G1.w + Bl1.w) / 3.0f;
  dt[0] = D0.x; dt[1] = D0.y; dt[2] = D0.z; dt[3] = D0.w;
  db_[0] = D1.x; db_[1] = D1.y; db_[2] = D1.z; db_[3] = D1.w;

  float oLL[2], oLH[2], oHL[2], oHH[2], oEr[2];
  float eLL[2], eLH[2], eHL[2], eHH[2], oEd[2];
  #pragma unroll
  for (int j = 0; j < 2; ++j) {
    float a = gt[2 * j] * 0.5f, bb = gb[2 * j] * 0.5f;
    float c = gt[2 * j + 1] * 0.5f, d = gb[2 * j + 1] * 0.5f;
    oLL[j] = a + bb; oLH[j] = a - bb; oHL[j] = c + d; oHH[j] = c - d;
    oEr[j] = sqrtf(oLH[j] * oLH[j] + oHL[j] * oHL[j] + oHH[j] * oHH[j] + 1e-8f);
    float da = dt[2 * j] * 0.5f, db2 = db_[2 * j] * 0.5f;
    float dc = dt[2 * j + 1] * 0.5f, dd = db_[2 * j + 1] * 0.5f;
    eLL[j] = da + db2; eLH[j] = da - db2; eHL[j] = dc + dd; eHH[j] = dc - dd;
    oEd[j] = sqrtf(eLH[j] * eLH[j] + eHL[j] * eHL[j] + eHH[j] * eHH[j] + 1e-8f);
  }
  float* f = freq + (size_t)bi * 12 * CHW + y * 512 + 2 * xp;
  *(float2*)(f + 0 * CHW) = make_float2(oLL[0], oLL[1]);
  *(float2*)(f + 1 * CHW) = make_float2(oLH[0], oLH[1]);
  *(float2*)(f + 2 * CHW) = make_float2(oHL[0], oHL[1]);
  *(float2*)(f + 3 * CHW) = make_float2(oHH[0], oHH[1]);
  *(float2*)(f + 4 * CHW) = make_float2(eLL[0], eLL[1]);
  *(float2*)(f + 5 * CHW) = make_float2(eLH[0], eLH[1]);
  *(float2*)(f + 6 * CHW) = make_float2(eHL[0], eHL[1]);
  *(float2*)(f + 7 * CHW) = make_float2(eHH[0], eHH[1]);
  *(float2*)(f + 8 * CHW) = make_float2(oEr[0], oEr[1]);
  *(float2*)(f + 9 * CHW) = make_float2(oEd[0], oEd[1]);
}

// ---------------------------------------------------------------- freq ch 10,11
__constant__ float GW[25] = {
  0.00296901f, 0.01330621f, 0.02193824f, 0.01330621f, 0.00296901f,
  0.01330621f, 0.05963435f, 0.09832035f, 0.05963435f, 0.01330621f,
  0.02193824f, 0.09832035f, 0.16210276f, 0.09832035f, 0.02193824f,
  0.01330621f, 0.05963435f, 0.09832035f, 0.05963435f, 0.01330621f,
  0.00296901f, 0.01330621f, 0.02193824f, 0.01330621f, 0.00296901f};

__global__ __launch_bounds__(256) void k_smooth(float* __restrict__ freq) {
  int t = blockIdx.x * 256 + threadIdx.x;
  int bi = blockIdx.y;
  int x = t & 511, y = t >> 9;
  float* fb_ = freq + (size_t)bi * 12 * CHW;
  #pragma unroll
  for (int ch = 0; ch < 2; ++ch) {
    const float* fin = fb_ + (8 + ch) * CHW;
    float acc = 0.0f;
    #pragma unroll
    for (int i = 0; i < 5; ++i) {
      int yy = y + i - 2;
      if (yy < 0 || yy > 511) continue;
      #pragma unroll
      for (int j = 0; j < 5; ++j) {
        int xx = x + j - 2;
        if (xx < 0 || xx > 511) continue;
        acc += GW[i * 5 + j] * fin[yy * 512 + xx];
      }
    }
    fb_[(10 + ch) * CHW + t] = acc;
  }
}

// ---------------------------------------------------------------- conv fused
// Block = 64x4 px tile, 4 waves. Wave w computes co in [8w, 8w+8) for ALL
// 256 tile px (4 horizontal px/thread). Weights: wave-uniform s_load.
// acc[4][8]=32 VGPR -> ~110 total -> 4 waves/SIMD. Epilogue: per-wave
// partial gelu-dot, cross-wave sum via LDS, sigmoid, store.
__device__ __forceinline__ void load_win(const float* __restrict__ fp, int y,
                                         int x0, float* __restrict__ v) {
  #pragma unroll
  for (int r = 0; r < 3; ++r) {
    int yy = y + r - 1;
    bool rv = (yy >= 0 && yy < 512);
    const float* rp = fp + yy * 512;
    float4 m = rv ? *(const float4*)(rp + x0) : make_float4(0.f, 0.f, 0.f, 0.f);
    v[r * 6 + 1] = m.x; v[r * 6 + 2] = m.y; v[r * 6 + 3] = m.z; v[r * 6 + 4] = m.w;
    v[r * 6 + 0] = (rv && x0 > 0) ? rp[x0 - 1] : 0.0f;
    v[r * 6 + 5] = (rv && x0 + 4 < 512) ? rp[x0 + 4] : 0.0f;
  }
}

__global__ __launch_bounds__(256) void k_conv(const float* __restrict__ freq,
    const float* __restrict__ wp, float* __restrict__ sal, int b0) {
  int lane = threadIdx.x;                        // 0..63 (one wave per ty)
  int wv = threadIdx.y;                          // 0..3 co-group
  int cw = __builtin_amdgcn_readfirstlane(wv) << 3;   // scalar co base
  int tx = lane & 15, row = lane >> 4;
  int x0 = blockIdx.x * 64 + tx * 4;
  int y  = blockIdx.y * 4 + row;
  int bi = blockIdx.z;
  const float* fb_ = freq + (size_t)bi * 12 * CHW;

  float acc[4][8];
  #pragma unroll
  for (int c = 0; c < 8; ++c) {
    float bv = wp[WP_B1 + cw + c];               // uniform -> SGPR
    acc[0][c] = bv; acc[1][c] = bv; acc[2][c] = bv; acc[3][c] = bv;
  }

  float v[18], nv[18];
  load_win(fb_, y, x0, v);

  auto fma_ci = [&](int ci, const float* win) {
    const float* wb = wp + ci * 288 + cw;        // uniform base
    #pragma unroll
    for (int ky = 0; ky < 3; ++ky) {
      #pragma unroll
      for (int kx = 0; kx < 3; ++kx) {
        const float* wk = wb + (ky * 3 + kx) * 32;
        float a0 = win[ky * 6 + kx],     a1 = win[ky * 6 + kx + 1];
        float a2 = win[ky * 6 + kx + 2], a3 = win[ky * 6 + kx + 3];
        #pragma unroll
        for (int c = 0; c < 8; ++c) {
          float t = wk[c];                       // uniform -> s_load
          acc[0][c] += t * a0;
          acc[1][c] += t * a1;
          acc[2][c] += t * a2;
          acc[3][c] += t * a3;
        }
      }
    }
  };

  #pragma unroll 1
  for (int ci = 0; ci < 12; ci += 2) {           // ping-pong windows
    load_win(fb_ + (ci + 1) * CHW, y, x0, nv);
    fma_ci(ci, v);
    if (ci + 2 < 12) load_win(fb_ + (ci + 2) * CHW, y, x0, v);
    fma_ci(ci + 1, nv);
  }

  float part[4];
  #pragma unroll
  for (int px = 0; px < 4; ++px) {
    float s = 0.0f;
    #pragma unroll
    for (int c = 0; c < 8; ++c) {
      float t = acc[px][c] * wp[WP_SC + cw + c] + wp[WP_SH + cw + c];
      float t3 = t * t * t;
      float gl = 0.5f * t * (1.0f + tanhf(0.7978845608028654f * (t + 0.044715f * t3)));
      s += gl * wp[WP_W2 + cw + c];
    }
    part[px] = s;
  }

  __shared__ __align__(16) float sRed[4][256];   // [wave][tile px]
  int pxid = row * 64 + tx * 4;
  *(float4*)&sRed[wv][pxid] = make_float4(part[0], part[1], part[2], part[3]);
  __syncthreads();
  int tid = wv * 64 + lane;                      // 0..255 -> one tile px
  float s2 = wp[WP_B2] + sRed[0][tid] + sRed[1][tid] + sRed[2][tid] + sRed[3][tid];
  float res = 1.0f / (1.0f + expf(-s2));
  int r2 = tid >> 6, c2 = tid & 63;
  sal[(size_t)(b0 + bi) * CHW + (blockIdx.y * 4 + r2) * 512 + blockIdx.x * 64 + c2] = res;
}

// ---------------------------------------------------------------- resize + box partials
__global__ __launch_bounds__(256) void k_resize(const float* __restrict__ sal,
                                                float* __restrict__ masks,
                                                int* __restrict__ part) {
  int b = blockIdx.y;
  int blk = blockIdx.x;
  int t = threadIdx.x;
  const float* sp = sal + (size_t)b * CHW;
  float* mp = masks + (size_t)b * FULLHW;
  int mnX = 0x7FFFFFFF, mxX = -1, mnY = 0x7FFFFFFF, mxY = -1;
  int c0 = 4 * t;
  #pragma unroll
  for (int r = 0; r < 4; ++r) {
    int Y = blk * 4 + r;
    int y0 = (Y - 1) >> 1;
    float wy = (Y & 1) ? 0.25f : 0.75f;
    int y0c = y0 < 0 ? 0 : y0, y1c = (y0 + 1 > 511) ? 511 : y0 + 1;
    const float* r0 = sp + y0c * 512;
    const float* r1 = sp + y1c * 512;
    float o[4];
    #pragma unroll
    for (int j = 0; j < 4; ++j) {
      int X = c0 + j;
      int x0 = (X - 1) >> 1;
      float wx = (X & 1) ? 0.25f : 0.75f;
      int x0c = x0 < 0 ? 0 : x0, x1c = (x0 + 1 > 511) ? 511 : x0 + 1;
      float v00 = r0[x0c], v01 = r0[x1c], v10 = r1[x0c], v11 = r1[x1c];
      o[j] = (1.0f - wy) * ((1.0f - wx) * v00 + wx * v01)
           + wy * ((1.0f - wx) * v10 + wx * v11);
      if (o[j] > 0.5f) {
        mnX = min(mnX, X); mxX = max(mxX, X);
        mnY = min(mnY, Y); mxY = max(mxY, Y);
      }
    }
    *(float4*)(mp + (size_t)Y * 1024 + c0) = make_float4(o[0], o[1], o[2], o[3]);
  }
  __shared__ int s0[256], s1[256], s2[256], s3[256];
  s0[t] = mnX; s1[t] = mxX; s2[t] = mnY; s3[t] = mxY;
  __syncthreads();
  for (int off = 128; off > 0; off >>= 1) {
    if (t < off) {
      s0[t] = min(s0[t], s0[t + off]); s1[t] = max(s1[t], s1[t + off]);
      s2[t] = min(s2[t], s2[t + off]); s3[t] = max(s3[t], s3[t + off]);
    }
    __syncthreads();
  }
  if (t == 0) {
    int* pp = part + (b * 256 + blk) * 4;
    pp[0] = s0[0]; pp[1] = s1[0]; pp[2] = s2[0]; pp[3] = s3[0];
  }
}

// ---------------------------------------------------------------- box reduce -> out
__global__ __launch_bounds__(256) void k_boxreduce(const int* __restrict__ part,
                                                   float* __restrict__ out) {
  int b = blockIdx.x, t = threadIdx.x;
  const int* pp = part + (b * 256 + t) * 4;
  __shared__ int s0[256], s1[256], s2[256], s3[256];
  s0[t] = pp[0]; s1[t] = pp[1]; s2[t] = pp[2]; s3[t] = pp[3];
  __syncthreads();
  for (int off = 128; off > 0; off >>= 1) {
    if (t < off) {
      s0[t] = min(s0[t], s0[t + off]); s1[t] = max(s1[t], s1[t + off]);
      s2[t] = min(s2[t], s2[t + off]); s3[t] = max(s3[t], s3[t + off]);
    }
    __syncthreads();
  }
  if (t == 0) {
    float x0, y0, x1, y1;
    if (s3[0] < 0) { x0 = 0.0f; y0 = 0.0f; x1 = 1023.0f; y1 = 1023.0f; }
    else { x0 = (float)s0[0]; y0 = (float)s2[0]; x1 = (float)s1[0]; y1 = (float)s3[0]; }
    out[240 + b * 4 + 0] = x0;
    out[240 + b * 4 + 1] = y0;
    out[240 + b * 4 + 2] = x1;
    out[240 + b * 4 + 3] = y1;
  }
}

// ---------------------------------------------------------------- peak helper
__device__ inline bool is_peak(const float* __restrict__ sp, int x, int y, float& sv) {
  float s = sp[y * 512 + x];
  sv = s;
  if (!(s > 0.0f)) return false;
  int x0 = (x > 0) ? x - 1 : x, x1 = (x < 511) ? x + 1 : x;
  int y0 = (y > 0) ? y - 1 : y, y1 = (y < 511) ? y + 1 : y;
  for (int yy = y0; yy <= y1; ++yy)
    for (int xx = x0; xx <= x1; ++xx)
      if (sp[yy * 512 + xx] > s) return false;     // s >= all neighbors == (s==maxpool)
  return true;
}

// ---------------------------------------------------------------- level-1 hist (+peak mask)
__global__ __launch_bounds__(256) void k_hist1(const float* __restrict__ sal,
                                               unsigned* __restrict__ hist,
                                               unsigned char* __restrict__ pkm) {
  __shared__ unsigned sH[4096];                   // [class][2048]
  int b = blockIdx.y, tid = threadIdx.x;
  for (int i = tid; i < 4096; i += 256) sH[i] = 0;
  __syncthreads();
  const float* sp = sal + (size_t)b * CHW;
  int base = blockIdx.x * 2048;
  for (int it = 0; it < 8; ++it) {
    int p = base + it * 256 + tid;
    int x = p & 511, y = p >> 9;
    float s;
    bool pk = is_peak(sp, x, y, s);
    pkm[(size_t)b * CHW + p] = pk ? 1 : 0;
    unsigned bin = (__float_as_uint(s) >> 21) & 2047;
    atomicAdd(&sH[(pk ? 0 : 2048) + bin], 1u);
  }
  __syncthreads();
  for (int i = tid; i < 4096; i += 256) {
    unsigned v = sH[i];
    if (v) atomicAdd(&hist[(i >= 2048 ? 16384 : 0) + b * 2048 + (i & 2047)], v);
  }
}

// ---------------------------------------------------------------- radix scan
__global__ __launch_bounds__(256) void k_scan(const unsigned* __restrict__ hist,
                                              int* __restrict__ thr, int level) {
  int c = blockIdx.x, b = blockIdx.y, t = threadIdx.x;
  __shared__ unsigned sBins[2048];
  __shared__ unsigned sS[256];
  __shared__ int sT;
  const unsigned* hp = hist + c * 16384 + b * 2048;
  unsigned part = 0;
  for (int r = 0; r < 8; ++r) {
    unsigned v = hp[t * 8 + r];
    sBins[t * 8 + r] = v;
    part += v;
  }
  sS[t] = part;
  __syncthreads();
  for (int off = 1; off < 256; off <<= 1) {
    unsigned add = (t + off < 256) ? sS[t + off] : 0;
    __syncthreads();
    sS[t] += add;
    __syncthreads();
  }
  int K = (c == 0) ? 512 : 10;
  int* tb = thr + (c * 8 + b) * 4;
  if (level == 1) { K -= tb[1]; if (K < 1) K = 1; }
  if (t == 0) sT = -1;
  __syncthreads();
  if (sS[t] >= (unsigned)K && (t == 255 || sS[t + 1] < (unsigned)K)) sT = t;
  __syncthreads();
  if (t == 0) {
    int T = 0;
    unsigned run = 0;
    if (sT >= 0) {
      int ts = sT;
      run = (ts < 255) ? sS[ts + 1] : 0;
      for (int r = 7; r >= 0; --r) {
        unsigned v = sBins[ts * 8 + r];
        run += v;
        if (run >= (unsigned)K) { T = ts * 8 + r; run -= v; break; }
      }
    } else {
      T = 0;
      run = sS[0] - sBins[0];                     // suffix(1); take everything
    }
    if (level == 0) { tb[0] = T; tb[1] = (int)run; }
    else           { tb[2] = (tb[0] << 11) | T; }
  }
}

// ---------------------------------------------------------------- level-2 hist
__global__ __launch_bounds__(256) void k_hist2(const float* __restrict__ sal,
                                               const unsigned char* __restrict__ pkm,
                                               const int* __restrict__ thr,
                                               unsigned* __restrict__ hist2) {
  int b = blockIdx.y;
  int p = blockIdx.x * 256 + threadIdx.x;
  const float* sp = sal + (size_t)b * CHW;
  bool pk = pkm[(size_t)b * CHW + p] != 0;
  float s = sp[p];
  int c = pk ? 0 : 1;
  unsigned bits = __float_as_uint(s);
  if ((int)(bits >> 21) == thr[(c * 8 + b) * 4])
    atomicAdd(&hist2[c * 16384 + b * 2048 + ((bits >> 10) & 2047)], 1u);
}

// ---------------------------------------------------------------- compact
__global__ __launch_bounds__(256) void k_compact(const float* __restrict__ sal,
                                                 const unsigned char* __restrict__ pkm,
                                                 const int* __restrict__ thr,
                                                 unsigned* __restrict__ cnt,
                                                 unsigned long long* __restrict__ cand) {
  int b = blockIdx.y;
  int p = blockIdx.x * 256 + threadIdx.x;
  const float* sp = sal + (size_t)b * CHW;
  bool pk = pkm[(size_t)b * CHW + p] != 0;
  float s = sp[p];
  int c = pk ? 0 : 1;
  unsigned bits = __float_as_uint(s);
  unsigned q = (unsigned)thr[(c * 8 + b) * 4 + 2];
  if ((bits >> 10) >= q) {
    unsigned pos = atomicAdd(&cnt[c * 8 + b], 1u);
    if (pos < 1024)
      cand[((size_t)(c * 8 + b) << 10) + pos] =
          ((unsigned long long)bits << 32) | (unsigned)(~p);   // score desc, idx asc
  }
}

// ---------------------------------------------------------------- sort + NMS
__device__ inline void bitonic1024_desc(unsigned long long* sKey) {
  int t = threadIdx.x;
  for (unsigned k = 2; k <= 1024; k <<= 1) {
    for (unsigned j = k >> 1; j > 0; j >>= 1) {
      __syncthreads();
      #pragma unroll
      for (int e = 0; e < 2; ++e) {
        unsigned i = (unsigned)t + (unsigned)e * 512u;
        unsigned l = i ^ j;
        if (l > i) {
          unsigned long long a = sKey[i], bb = sKey[l];
          if (((i & k) == 0) ? (a < bb) : (a > bb)) { sKey[i] = bb; sKey[l] = a; }
        }
      }
    }
  }
  __syncthreads();
}

__global__ __launch_bounds__(512) void k_nms(const unsigned long long* __restrict__ cand,
                                             const unsigned* __restrict__ cnt,
                                             float* __restrict__ out) {
  __shared__ unsigned long long sKey[1024];
  __shared__ unsigned sIdx[512];
  __shared__ int sAvail[512];
  __shared__ int sSel[16];
  int b = blockIdx.x, t = threadIdx.x;
  if (t < 10) out[160 + b * 10 + t] = 1.0f;       // labels
  int Cp = (int)cnt[b]; if (Cp > 1024) Cp = 1024;
  const unsigned long long* cp = cand + ((size_t)b << 10);
  sKey[t] = (t < Cp) ? cp[t] : 0ULL;
  sKey[t + 512] = (t + 512 < Cp) ? cp[t + 512] : 0ULL;
  bitonic1024_desc(sKey);
  sIdx[t] = (unsigned)(~sKey[t]);
  int ncand = (Cp < 512) ? Cp : 512;              // K_PEAKS cap
  sAvail[t] = (t < ncand) ? 1 : 0;
  __syncthreads();
  int nsel = 0;
  for (int i = 0; i < 512 && nsel < 10; ++i) {
    if (sAvail[i] != 0) {                         // uniform branch
      unsigned pi = sIdx[i];
      int xi = (int)(pi & 511), yi = (int)(pi >> 9);
      if (t > i && sAvail[t]) {
        int dx = (int)(sIdx[t] & 511) - xi;
        int dy = (int)(sIdx[t] >> 9) - yi;
        if (dx * dx + dy * dy < 625) sAvail[t] = 0;   // dist < 25
      }
      if (t == 0) sSel[nsel] = (int)pi;
      ++nsel;
      __syncthreads();
    }
  }
  __syncthreads();
  // fallback: top-10 non-peak pixels
  int Cf = (int)cnt[8 + b]; if (Cf > 1024) Cf = 1024;
  const unsigned long long* cf = cand + ((size_t)(8 + b) << 10);
  sKey[t] = (t < Cf) ? cf[t] : 0ULL;
  sKey[t + 512] = (t + 512 < Cf) ? cf[t + 512] : 0ULL;
  bitonic1024_desc(sKey);
  if (t < 10) {
    int fi;
    if (t < nsel) fi = sSel[t];
    else { int r = t - nsel; if (r > 9) r = 9; fi = (int)((unsigned)(~sKey[r])); }
    out[((size_t)b * 10 + t) * 2 + 0] = (float)(fi & 511) * (1.0f / 512.0f);
    out[((size_t)b * 10 + t) * 2 + 1] = (float)(fi >> 9) * (1.0f / 512.0f);
  }
}

// ---------------------------------------------------------------------------
extern "C" void kernel_launch(void* const* d_in, const int* in_sizes, int n_in,
                              void* d_out, int out_size, void* d_ws, size_t ws_size,
                              hipStream_t stream) {
  const float* rgb  = (const float*)d_in[0];
  const float* dep  = (const float*)d_in[1];
  const float* w1   = (const float*)d_in[2];
  const float* b1   = (const float*)d_in[3];
  const float* gam  = (const float*)d_in[4];
  const float* bet  = (const float*)d_in[5];
  const float* bmn  = (const float*)d_in[6];
  const float* bvr  = (const float*)d_in[7];
  const float* w2   = (const float*)d_in[8];
  const float* b2   = (const float*)d_in[9];
  float* out = (float*)d_out;
  char* ws = (char*)d_ws;

  float* sal = (float*)(ws + OFF_SAL);
  unsigned* hist1 = (unsigned*)(ws + OFF_HIST1);
  unsigned* hist2 = (unsigned*)(ws + OFF_HIST2);
  int* thr = (int*)(ws + OFF_THR);
  unsigned* cnt = (unsigned*)(ws + OFF_CNT);
  unsigned long long* cand = (unsigned long long*)(ws + OFF_CAND);
  int* part = (int*)(ws + OFF_PART);
  float* wpack = (float*)(ws + OFF_WPACK);
  unsigned char* pkm = (unsigned char*)(ws + OFF_PKM);
  float* freq = (float*)(ws + OFF_FREQ);

  // chunk batches so freq buffer fits in ws
  size_t perB = (size_t)12 * CHW * 4;
  long long avail = (long long)ws_size - (long long)OFF_FREQ;
  int nb = 1;
  if (avail >= (long long)perB) {
    long long m = avail / (long long)perB;
    nb = (m > 8) ? 8 : (int)m;
  }

  k_init<<<256, 256, 0, stream>>>(hist1, cnt, w1, b1, gam, bet, bmn, bvr, w2, b2,
                                  wpack);

  for (int b0 = 0; b0 < 8; b0 += nb) {
    int nbc = (8 - b0 < nb) ? (8 - b0) : nb;
    k_freq<<<dim3(512, nbc), 256, 0, stream>>>(rgb, dep, freq, b0);
    k_smooth<<<dim3(1024, nbc), 256, 0, stream>>>(freq);
    k_conv<<<dim3(8, 128, nbc), dim3(64, 4), 0, stream>>>(freq, wpack, sal, b0);
  }

  k_resize<<<dim3(256, 8), 256, 0, stream>>>(sal, out + 272, part);
  k_boxreduce<<<8, 256, 0, stream>>>(part, out);
  k_hist1<<<dim3(128, 8), 256, 0, stream>>>(sal, hist1, pkm);
  k_scan<<<dim3(2, 8), 256, 0, stream>>>(hist1, thr, 0);
  k_hist2<<<dim3(1024, 8), 256, 0, stream>>>(sal, pkm, thr, hist2);
  k_scan<<<dim3(2, 8), 256, 0, stream>>>(hist2, thr, 1);
  k_compact<<<dim3(1024, 8), 256, 0, stream>>>(sal, pkm, thr, cnt, cand);
  k_nms<<<8, 512, 0, stream>>>(cand, cnt, out);
}